// Round 4
// baseline (124.475 us; speedup 1.0000x reference)
//
#include <hip/hip_runtime.h>
#include <math.h>

#define LL 4096
#define BB 2048
#define NT 512
#define CH 8                      // contiguous elements per thread; NT*CH == LL
#define ALPHA 1.0f
#define BETA 0.5f
#define NEG_INF (-__builtin_inff())
#define POS_INF (__builtin_inff())

// Padded LDS layout: logical position i in [-24, LL+23] lives at i + (i>>3) + 27.
// IDX(8t + d) == 9t + (d + (d>>3) + 27) -> with base = arr + 9t, every offset the
// eval needs is a compile-time immediate; lane stride 9 dwords => conflict-free.
#define SPSZ 4672                 // > IDX(LL+23) = 4660
#define OFS(d) ((d) + ((d) >> 3) + 27)

// ---- DPP wave64 sum reduction (VALU pipe, no LDS/bpermute) ----
template <int CTRL, int RM>
__device__ __forceinline__ float dpp_addf(float v) {
    int s = __builtin_amdgcn_update_dpp(0, __float_as_int(v), CTRL, RM, 0xf, true);
    return v + __int_as_float(s);
}
__device__ __forceinline__ float wredf(float v) {
    v = dpp_addf<0x111, 0xf>(v);   // row_shr:1
    v = dpp_addf<0x112, 0xf>(v);   // row_shr:2
    v = dpp_addf<0x114, 0xf>(v);   // row_shr:4
    v = dpp_addf<0x118, 0xf>(v);   // row_shr:8  -> lane15 of each row = row sum
    v = dpp_addf<0x142, 0xa>(v);   // row_bcast:15 into rows 1,3
    v = dpp_addf<0x143, 0xc>(v);   // row_bcast:31 into rows 2,3
    return v;                      // total in lane 63
}

__global__ __launch_bounds__(NT, 8) void row_kernel(const float* __restrict__ gA,
                                                    const float* __restrict__ gB,
                                                    float* __restrict__ out) {
    __shared__ float sS[SPSZ];     // suffix-max within 8-aligned chunk (+ -inf margins)
    __shared__ float sP[SPSZ];     // prefix-max within 8-aligned chunk (+ -inf margins)
    __shared__ float4 red4[NT / 64][2];   // per-wave partials, float4-packed

    const int b = blockIdx.x;
    const int t = threadIdx.x;
    float* const Sb = sS + 9 * t;
    float* const Pb = sP + 9 * t;
    const float* rowA = gA + (size_t)b * LL;
    const float* rowB = gB + (size_t)b * LL;

    // ---- load both chunks straight to registers (32 B contiguous per thread) ----
    float xA[CH], xB[CH];
    {
        const float4* a4 = (const float4*)rowA;
        const float4* b4 = (const float4*)rowB;
#pragma unroll
        for (int k = 0; k < CH / 4; ++k) {
            float4 v = a4[t * (CH / 4) + k];
            xA[4 * k + 0] = v.x; xA[4 * k + 1] = v.y; xA[4 * k + 2] = v.z; xA[4 * k + 3] = v.w;
            float4 u = b4[t * (CH / 4) + k];
            xB[4 * k + 0] = u.x; xB[4 * k + 1] = u.y; xB[4 * k + 2] = u.z; xB[4 * k + 3] = u.w;
        }
    }

    // ---- fused row stats ----
    float se = 0.f, dt = 0.f, na = 0.f, nb = 0.f;
#pragma unroll
    for (int j = 0; j < CH; ++j) {
        float d = xA[j] - xB[j];
        se += d * d;
        dt += xA[j] * xB[j];
        na += xA[j] * xA[j];
        nb += xB[j] * xB[j];
    }

    // ---- -inf margins (logical i in [-24,-1] and [LL, LL+23]) ----
    if (t < 24) {
        int i = t - 24;
        int p = i + (i >> 3) + 27;
        sS[p] = NEG_INF; sP[p] = NEG_INF;
    } else if (t >= NT - 24) {
        int i = LL + (t - (NT - 24));
        int p = i + (i >> 3) + 27;
        sS[p] = NEG_INF; sP[p] = NEG_INF;
    }

    // ---- per-signal: scan -> LDS, barrier, branchless eval (all imm offsets) ----
    auto process = [&](const float (&x)[CH], int& cnt20, unsigned& m10) {
        float pp[CH], ss[CH];
        pp[0] = x[0];
#pragma unroll
        for (int j = 1; j < CH; ++j) pp[j] = fmaxf(pp[j - 1], x[j]);
        ss[CH - 1] = x[CH - 1];
#pragma unroll
        for (int j = CH - 2; j >= 0; --j) ss[j] = fmaxf(ss[j + 1], x[j]);
#pragma unroll
        for (int j = 0; j < CH; ++j) {
            Pb[j + 27] = pp[j];    // contiguous -> ds_write2_b32 pairs
            Sb[j + 27] = ss[j];
        }
        const float cmax = pp[CH - 1];
        __syncthreads();

        // neighbor chunk maxes: C(t+k) = P[last elem of chunk t+k]
        const float Cm2 = Pb[OFS(-9)];    // 16
        const float Cm1 = Pb[OFS(-1)];    // 25
        const float Cp1 = Pb[OFS(15)];    // 43
        const float Cp2 = Pb[OFS(23)];    // 52
        const float f1 = fmaxf(Cm1, cmax);
        const float f2 = fmaxf(cmax, Cp1);
        const float g2 = fmaxf(f1, Cp1);
        const float g1 = fmaxf(g2, Cm2);
        const float g3 = fmaxf(g2, Cp2);
        const float xm1 = (t == 0)      ? POS_INF : Sb[OFS(-1)];   // x[base-1]
        const float xp1 = (t == NT - 1) ? POS_INF : Pb[OFS(8)];    // x[base+8]

        cnt20 = 0; m10 = 0u;
#pragma unroll
        for (int j = 0; j < CH; ++j) {
            float xi = x[j];
            float xl = (j > 0)      ? x[j - 1] : xm1;
            float xr = (j < CH - 1) ? x[j + 1] : xp1;
            bool lm = (xi > xl) && (xi > xr);
            float a19 = Sb[OFS(j - 9)];
            float b19 = Pb[OFS(j + 9)];
            float a39 = Sb[OFS(j - 19)];
            float b39 = Pb[OFS(j + 19)];
            float mid19 = (j == 0) ? f1 : ((j == CH - 1) ? f2 : cmax);
            float mid39 = (j <= 2) ? g1 : ((j <= 4) ? g2 : g3);
            float p19 = fmaxf(fmaxf(a19, b19), mid19);
            float p39 = fmaxf(fmaxf(a39, b39), mid39);
            if (lm && xi >= p19) m10 |= (1u << j);
            if (lm && xi >= p39) cnt20++;
        }
    };

    int cntA, cntB;
    unsigned mA, mB;
    process(xA, cntA, mA);
    __syncthreads();              // evalA reads done before scanB overwrites
    process(xB, cntB, mB);

    // ---- peak-to-peak squared error (positions aligned per thread) ----
    float p2p = 0.f;
#pragma unroll
    for (int j = 0; j < CH; ++j) {
        float av = ((mA >> j) & 1u) ? xA[j] : 0.f;
        float bv = ((mB >> j) & 1u) ? xB[j] : 0.f;
        float d = av - bv;
        p2p += d * d;
    }

    // ---- wave reductions on VALU (DPP), totals land in lane 63 ----
    se = wredf(se); dt = wredf(dt); na = wredf(na); nb = wredf(nb); p2p = wredf(p2p);
    float cA = wredf((float)cntA);
    float cB = wredf((float)cntB);

    if ((t & 63) == 63) {
        int w = t >> 6;
        red4[w][0] = make_float4(se, dt, na, nb);
        red4[w][1] = make_float4(p2p, cA, cB, 0.f);
    }
    __syncthreads();
    if (t == 0) {
        float s0 = 0, s1 = 0, s2 = 0, s3 = 0, s4 = 0, s5 = 0, s6 = 0;
#pragma unroll
        for (int i = 0; i < NT / 64; ++i) {
            float4 u = red4[i][0];
            float4 v = red4[i][1];
            s0 += u.x; s1 += u.y; s2 += u.z; s3 += u.w;
            s4 += v.x; s5 += v.y; s6 += v.z;
        }
        float mse_i = s0 / (float)LL;
        float cos_i = s1 / (sqrtf(s2) * sqrtf(s3));
        float p2p_i = s4 / (float)LL;
        float custom_i = (s5 != s6) ? (mse_i * ALPHA) : (p2p_i * BETA);
        const float invB = 1.0f / (float)BB;
        atomicAdd(out + 0, mse_i * invB + custom_i);   // total = mean(mse) + sum(custom)
        atomicAdd(out + 1, cos_i * invB);              // mean cosine
        atomicAdd(out + 2, p2p_i);                     // sum p2p
        atomicAdd(out + 3, mse_i * invB);              // mean mse
    }
}

extern "C" void kernel_launch(void* const* d_in, const int* in_sizes, int n_in,
                              void* d_out, int out_size, void* d_ws, size_t ws_size,
                              hipStream_t stream) {
    const float* inA = (const float*)d_in[0];   // in_signal
    const float* inB = (const float*)d_in[1];   // ref_signal
    float* out = (float*)d_out;

    hipMemsetAsync(out, 0, out_size * sizeof(float), stream);   // capturable memset node
    hipLaunchKernelGGL(row_kernel, dim3(BB), dim3(NT), 0, stream, inA, inB, out);
}

// Round 5
// 119.735 us; speedup vs baseline: 1.0396x; 1.0396x over previous
//
#include <hip/hip_runtime.h>
#include <math.h>

#define LL 4096
#define BB 2048
#define NT 512
#define CH 8                      // contiguous elements per thread; NT*CH == LL
#define ALPHA 1.0f
#define BETA 0.5f
#define NEG_INF (-__builtin_inff())
#define POS_INF (__builtin_inff())

// Padded LDS layout: logical position i in [-24, LL+23] lives at i + (i>>3) + 27.
// IDX(8t + d) == 9t + (d + (d>>3) + 27) -> with base = arr + 9t, every offset the
// eval needs is a compile-time immediate; lane stride 9 dwords => conflict-free.
#define SPSZ 4672                 // > IDX(LL+23) = 4660
#define OFS(d) ((d) + ((d) >> 3) + 27)

// ---- DPP wave64 sum reduction (VALU pipe, no LDS/bpermute) ----
template <int CTRL, int RM>
__device__ __forceinline__ float dpp_addf(float v) {
    int s = __builtin_amdgcn_update_dpp(0, __float_as_int(v), CTRL, RM, 0xf, true);
    return v + __int_as_float(s);
}
__device__ __forceinline__ float wredf(float v) {
    v = dpp_addf<0x111, 0xf>(v);   // row_shr:1
    v = dpp_addf<0x112, 0xf>(v);   // row_shr:2
    v = dpp_addf<0x114, 0xf>(v);   // row_shr:4
    v = dpp_addf<0x118, 0xf>(v);   // row_shr:8  -> lane15 of each row = row sum
    v = dpp_addf<0x142, 0xa>(v);   // row_bcast:15 into rows 1,3
    v = dpp_addf<0x143, 0xc>(v);   // row_bcast:31 into rows 2,3
    return v;                      // total in lane 63
}

__global__ __launch_bounds__(NT, 6) void row_kernel(const float* __restrict__ gA,
                                                    const float* __restrict__ gB,
                                                    float* __restrict__ out) {
    __shared__ float sS[SPSZ];     // suffix-max within 8-aligned chunk (+ -inf margins)
    __shared__ float sP[SPSZ];     // prefix-max within 8-aligned chunk (+ -inf margins)
    __shared__ float4 red4[NT / 64][2];   // per-wave partials, float4-packed

    const int b = blockIdx.x;
    const int t = threadIdx.x;
    float* const Sb = sS + 9 * t;
    float* const Pb = sP + 9 * t;
    const float* rowA = gA + (size_t)b * LL;
    const float* rowB = gB + (size_t)b * LL;

    // ---- load both chunks straight to registers (32 B contiguous per thread) ----
    float xA[CH], xB[CH];
    {
        const float4* a4 = (const float4*)rowA;
        const float4* b4 = (const float4*)rowB;
#pragma unroll
        for (int k = 0; k < CH / 4; ++k) {
            float4 v = a4[t * (CH / 4) + k];
            xA[4 * k + 0] = v.x; xA[4 * k + 1] = v.y; xA[4 * k + 2] = v.z; xA[4 * k + 3] = v.w;
            float4 u = b4[t * (CH / 4) + k];
            xB[4 * k + 0] = u.x; xB[4 * k + 1] = u.y; xB[4 * k + 2] = u.z; xB[4 * k + 3] = u.w;
        }
    }

    // ---- fused row stats; reduce NOW (low register pressure) and retire to LDS ----
    {
        float se = 0.f, dt = 0.f, na = 0.f, nb = 0.f;
#pragma unroll
        for (int j = 0; j < CH; ++j) {
            float d = xA[j] - xB[j];
            se += d * d;
            dt += xA[j] * xB[j];
            na += xA[j] * xA[j];
            nb += xB[j] * xB[j];
        }
        se = wredf(se); dt = wredf(dt); na = wredf(na); nb = wredf(nb);
        if ((t & 63) == 63) red4[t >> 6][0] = make_float4(se, dt, na, nb);
    }

    // ---- -inf margins (logical i in [-24,-1] and [LL, LL+23]) ----
    if (t < 24) {
        int i = t - 24;
        int p = i + (i >> 3) + 27;
        sS[p] = NEG_INF; sP[p] = NEG_INF;
    } else if (t >= NT - 24) {
        int i = LL + (t - (NT - 24));
        int p = i + (i >> 3) + 27;
        sS[p] = NEG_INF; sP[p] = NEG_INF;
    }

    // ---- per-signal: scan -> LDS, barrier, branchless eval (all imm offsets) ----
    auto process = [&](const float (&x)[CH], int& cnt20, unsigned& m10) {
        float pp[CH], ss[CH];
        pp[0] = x[0];
#pragma unroll
        for (int j = 1; j < CH; ++j) pp[j] = fmaxf(pp[j - 1], x[j]);
        ss[CH - 1] = x[CH - 1];
#pragma unroll
        for (int j = CH - 2; j >= 0; --j) ss[j] = fmaxf(ss[j + 1], x[j]);
#pragma unroll
        for (int j = 0; j < CH; ++j) {
            Pb[j + 27] = pp[j];    // contiguous -> ds_write2_b32 pairs
            Sb[j + 27] = ss[j];
        }
        const float cmax = pp[CH - 1];
        __syncthreads();

        // neighbor chunk maxes: C(t+k) = P[last elem of chunk t+k]
        const float Cm2 = Pb[OFS(-9)];
        const float Cm1 = Pb[OFS(-1)];
        const float Cp1 = Pb[OFS(15)];
        const float Cp2 = Pb[OFS(23)];
        const float f1 = fmaxf(Cm1, cmax);
        const float f2 = fmaxf(cmax, Cp1);
        const float g2 = fmaxf(f1, Cp1);
        const float g1 = fmaxf(g2, Cm2);
        const float g3 = fmaxf(g2, Cp2);
        const float xm1 = (t == 0)      ? POS_INF : Sb[OFS(-1)];   // x[base-1]
        const float xp1 = (t == NT - 1) ? POS_INF : Pb[OFS(8)];    // x[base+8]

        cnt20 = 0; m10 = 0u;
#pragma unroll
        for (int j = 0; j < CH; ++j) {
            float xi = x[j];
            float xl = (j > 0)      ? x[j - 1] : xm1;
            float xr = (j < CH - 1) ? x[j + 1] : xp1;
            bool lm = (xi > xl) && (xi > xr);
            float a19 = Sb[OFS(j - 9)];
            float b19 = Pb[OFS(j + 9)];
            float a39 = Sb[OFS(j - 19)];
            float b39 = Pb[OFS(j + 19)];
            float mid19 = (j == 0) ? f1 : ((j == CH - 1) ? f2 : cmax);
            float mid39 = (j <= 2) ? g1 : ((j <= 4) ? g2 : g3);
            float p19 = fmaxf(fmaxf(a19, b19), mid19);
            float p39 = fmaxf(fmaxf(a39, b39), mid39);
            if (lm && xi >= p19) m10 |= (1u << j);
            if (lm && xi >= p39) cnt20++;
        }
    };

    int cntA, cntB;
    unsigned mA, mB;
    process(xA, cntA, mA);
    __syncthreads();              // evalA reads done before scanB overwrites
    process(xB, cntB, mB);

    // ---- peak-to-peak squared error (positions aligned per thread) ----
    float p2p = 0.f;
#pragma unroll
    for (int j = 0; j < CH; ++j) {
        float av = ((mA >> j) & 1u) ? xA[j] : 0.f;
        float bv = ((mB >> j) & 1u) ? xB[j] : 0.f;
        float d = av - bv;
        p2p += d * d;
    }

    // ---- tail reductions: only 2 DPP chains live (p2p, packed counts) ----
    p2p = wredf(p2p);
    float cc = wredf((float)(cntA * 4096 + cntB));   // exact: counts <= ~216/row
    if ((t & 63) == 63) red4[t >> 6][1] = make_float4(p2p, cc, 0.f, 0.f);
    __syncthreads();

    if (t == 0) {
        float s0 = 0, s1 = 0, s2 = 0, s3 = 0, s4 = 0, s5 = 0;
#pragma unroll
        for (int i = 0; i < NT / 64; ++i) {
            float4 u = red4[i][0];
            float4 v = red4[i][1];
            s0 += u.x; s1 += u.y; s2 += u.z; s3 += u.w;
            s4 += v.x; s5 += v.y;
        }
        int packed = (int)s5;
        int ca = packed >> 12;
        int cb = packed & 4095;
        float mse_i = s0 / (float)LL;
        float cos_i = s1 / (sqrtf(s2) * sqrtf(s3));
        float p2p_i = s4 / (float)LL;
        float custom_i = (ca != cb) ? (mse_i * ALPHA) : (p2p_i * BETA);
        const float invB = 1.0f / (float)BB;
        atomicAdd(out + 0, mse_i * invB + custom_i);   // total = mean(mse) + sum(custom)
        atomicAdd(out + 1, cos_i * invB);              // mean cosine
        atomicAdd(out + 2, p2p_i);                     // sum p2p
        atomicAdd(out + 3, mse_i * invB);              // mean mse
    }
}

extern "C" void kernel_launch(void* const* d_in, const int* in_sizes, int n_in,
                              void* d_out, int out_size, void* d_ws, size_t ws_size,
                              hipStream_t stream) {
    const float* inA = (const float*)d_in[0];   // in_signal
    const float* inB = (const float*)d_in[1];   // ref_signal
    float* out = (float*)d_out;

    hipMemsetAsync(out, 0, out_size * sizeof(float), stream);   // capturable memset node
    hipLaunchKernelGGL(row_kernel, dim3(BB), dim3(NT), 0, stream, inA, inB, out);
}

// Round 6
// 24.570 us; speedup vs baseline: 5.0662x; 4.8732x over previous
//
#include <hip/hip_runtime.h>
#include <math.h>

#define LL 4096
#define BB 2048
#define NT 512
#define CH 8                      // contiguous elements per thread; NT*CH == LL
#define ALPHA 1.0f
#define BETA 0.5f
#define NEG_INF (-__builtin_inff())
#define POS_INF (__builtin_inff())

// Padded LDS layout: logical position i in [-24, LL+23] lives at i + (i>>3) + 27.
// IDX(8t + d) == 9t + (d + (d>>3) + 27) -> with base = arr + 9t, every offset the
// eval needs is a compile-time immediate; lane stride 9 dwords => conflict-free.
#define SPSZ 4672                 // > IDX(LL+23) = 4660
#define OFS(d) ((d) + ((d) >> 3) + 27)

// ---- DPP wave64 sum reduction (VALU pipe, no LDS/bpermute) ----
template <int CTRL, int RM>
__device__ __forceinline__ float dpp_addf(float v) {
    int s = __builtin_amdgcn_update_dpp(0, __float_as_int(v), CTRL, RM, 0xf, true);
    return v + __int_as_float(s);
}
__device__ __forceinline__ float wredf(float v) {
    v = dpp_addf<0x111, 0xf>(v);   // row_shr:1
    v = dpp_addf<0x112, 0xf>(v);   // row_shr:2
    v = dpp_addf<0x114, 0xf>(v);   // row_shr:4
    v = dpp_addf<0x118, 0xf>(v);   // row_shr:8  -> lane15 of each row = row sum
    v = dpp_addf<0x142, 0xa>(v);   // row_bcast:15 into rows 1,3
    v = dpp_addf<0x143, 0xc>(v);   // row_bcast:31 into rows 2,3
    return v;                      // total in lane 63
}

__global__ __launch_bounds__(NT, 6) void row_kernel(const float* __restrict__ gA,
                                                    const float* __restrict__ gB,
                                                    float4* __restrict__ rowout) {
    __shared__ float sS[SPSZ];     // suffix-max within 8-aligned chunk (+ -inf margins)
    __shared__ float sP[SPSZ];     // prefix-max within 8-aligned chunk (+ -inf margins)
    __shared__ float4 red4[NT / 64][2];   // per-wave partials, float4-packed

    const int b = blockIdx.x;
    const int t = threadIdx.x;
    float* const Sb = sS + 9 * t;
    float* const Pb = sP + 9 * t;
    const float* rowA = gA + (size_t)b * LL;
    const float* rowB = gB + (size_t)b * LL;

    // ---- load both chunks straight to registers (32 B contiguous per thread) ----
    float xA[CH], xB[CH];
    {
        const float4* a4 = (const float4*)rowA;
        const float4* b4 = (const float4*)rowB;
#pragma unroll
        for (int k = 0; k < CH / 4; ++k) {
            float4 v = a4[t * (CH / 4) + k];
            xA[4 * k + 0] = v.x; xA[4 * k + 1] = v.y; xA[4 * k + 2] = v.z; xA[4 * k + 3] = v.w;
            float4 u = b4[t * (CH / 4) + k];
            xB[4 * k + 0] = u.x; xB[4 * k + 1] = u.y; xB[4 * k + 2] = u.z; xB[4 * k + 3] = u.w;
        }
    }

    // ---- fused row stats; reduce NOW (low register pressure) and retire to LDS ----
    {
        float se = 0.f, dt = 0.f, na = 0.f, nb = 0.f;
#pragma unroll
        for (int j = 0; j < CH; ++j) {
            float d = xA[j] - xB[j];
            se += d * d;
            dt += xA[j] * xB[j];
            na += xA[j] * xA[j];
            nb += xB[j] * xB[j];
        }
        se = wredf(se); dt = wredf(dt); na = wredf(na); nb = wredf(nb);
        if ((t & 63) == 63) red4[t >> 6][0] = make_float4(se, dt, na, nb);
    }

    // ---- -inf margins (logical i in [-24,-1] and [LL, LL+23]) ----
    if (t < 24) {
        int i = t - 24;
        int p = i + (i >> 3) + 27;
        sS[p] = NEG_INF; sP[p] = NEG_INF;
    } else if (t >= NT - 24) {
        int i = LL + (t - (NT - 24));
        int p = i + (i >> 3) + 27;
        sS[p] = NEG_INF; sP[p] = NEG_INF;
    }

    // ---- per-signal: scan -> LDS, barrier, branchless eval (all imm offsets) ----
    auto process = [&](const float (&x)[CH], int& cnt20, unsigned& m10) {
        float pp[CH], ss[CH];
        pp[0] = x[0];
#pragma unroll
        for (int j = 1; j < CH; ++j) pp[j] = fmaxf(pp[j - 1], x[j]);
        ss[CH - 1] = x[CH - 1];
#pragma unroll
        for (int j = CH - 2; j >= 0; --j) ss[j] = fmaxf(ss[j + 1], x[j]);
#pragma unroll
        for (int j = 0; j < CH; ++j) {
            Pb[j + 27] = pp[j];    // contiguous -> ds_write2_b32 pairs
            Sb[j + 27] = ss[j];
        }
        const float cmax = pp[CH - 1];
        __syncthreads();

        // neighbor chunk maxes: C(t+k) = P[last elem of chunk t+k]
        const float Cm2 = Pb[OFS(-9)];
        const float Cm1 = Pb[OFS(-1)];
        const float Cp1 = Pb[OFS(15)];
        const float Cp2 = Pb[OFS(23)];
        const float f1 = fmaxf(Cm1, cmax);
        const float f2 = fmaxf(cmax, Cp1);
        const float g2 = fmaxf(f1, Cp1);
        const float g1 = fmaxf(g2, Cm2);
        const float g3 = fmaxf(g2, Cp2);
        const float xm1 = (t == 0)      ? POS_INF : Sb[OFS(-1)];   // x[base-1]
        const float xp1 = (t == NT - 1) ? POS_INF : Pb[OFS(8)];    // x[base+8]

        cnt20 = 0; m10 = 0u;
#pragma unroll
        for (int j = 0; j < CH; ++j) {
            float xi = x[j];
            float xl = (j > 0)      ? x[j - 1] : xm1;
            float xr = (j < CH - 1) ? x[j + 1] : xp1;
            bool lm = (xi > xl) && (xi > xr);
            float a19 = Sb[OFS(j - 9)];
            float b19 = Pb[OFS(j + 9)];
            float a39 = Sb[OFS(j - 19)];
            float b39 = Pb[OFS(j + 19)];
            float mid19 = (j == 0) ? f1 : ((j == CH - 1) ? f2 : cmax);
            float mid39 = (j <= 2) ? g1 : ((j <= 4) ? g2 : g3);
            float p19 = fmaxf(fmaxf(a19, b19), mid19);
            float p39 = fmaxf(fmaxf(a39, b39), mid39);
            if (lm && xi >= p19) m10 |= (1u << j);
            if (lm && xi >= p39) cnt20++;
        }
    };

    int cntA, cntB;
    unsigned mA, mB;
    process(xA, cntA, mA);
    __syncthreads();              // evalA reads done before scanB overwrites
    process(xB, cntB, mB);

    // ---- peak-to-peak squared error (positions aligned per thread) ----
    float p2p = 0.f;
#pragma unroll
    for (int j = 0; j < CH; ++j) {
        float av = ((mA >> j) & 1u) ? xA[j] : 0.f;
        float bv = ((mB >> j) & 1u) ? xB[j] : 0.f;
        float d = av - bv;
        p2p += d * d;
    }

    // ---- tail reductions: only 2 DPP chains live (p2p, packed counts) ----
    p2p = wredf(p2p);
    float cc = wredf((float)(cntA * 4096 + cntB));   // exact: block sums << 2^24
    if ((t & 63) == 63) red4[t >> 6][1] = make_float4(p2p, cc, 0.f, 0.f);
    __syncthreads();

    if (t == 0) {
        float s0 = 0, s1 = 0, s2 = 0, s3 = 0, s4 = 0, s5 = 0;
#pragma unroll
        for (int i = 0; i < NT / 64; ++i) {
            float4 u = red4[i][0];
            float4 v = red4[i][1];
            s0 += u.x; s1 += u.y; s2 += u.z; s3 += u.w;
            s4 += v.x; s5 += v.y;
        }
        int packed = (int)s5;
        int ca = packed >> 12;
        int cb = packed & 4095;
        float mse_i = s0 / (float)LL;
        float cos_i = s1 / (sqrtf(s2) * sqrtf(s3));
        float p2p_i = s4 / (float)LL;
        float custom_i = (ca != cb) ? (mse_i * ALPHA) : (p2p_i * BETA);
        rowout[b] = make_float4(mse_i, cos_i, p2p_i, custom_i);
    }
}

__global__ __launch_bounds__(256) void reduce_kernel(const float4* __restrict__ rows,
                                                     float* __restrict__ out) {
    __shared__ float red[4][4];
    float sx = 0.f, sy = 0.f, sz = 0.f, sw = 0.f;
    for (int r = threadIdx.x; r < BB; r += 256) {
        float4 v = rows[r];
        sx += v.x; sy += v.y; sz += v.z; sw += v.w;
    }
    sx = wredf(sx); sy = wredf(sy); sz = wredf(sz); sw = wredf(sw);
    int w = threadIdx.x >> 6, lane = threadIdx.x & 63;
    if (lane == 63) { red[w][0] = sx; red[w][1] = sy; red[w][2] = sz; red[w][3] = sw; }
    __syncthreads();
    if (threadIdx.x == 0) {
        float ax = 0, ay = 0, az = 0, aw = 0;
        for (int i = 0; i < 4; ++i) {
            ax += red[i][0]; ay += red[i][1]; az += red[i][2]; aw += red[i][3];
        }
        float mse = ax / (float)BB;
        out[0] = mse + aw;          // total_loss = mse_loss + custom_loss
        out[1] = ay / (float)BB;    // mean cosine similarity
        out[2] = az;                // p2p_loss
        out[3] = mse;               // mse_loss
    }
}

extern "C" void kernel_launch(void* const* d_in, const int* in_sizes, int n_in,
                              void* d_out, int out_size, void* d_ws, size_t ws_size,
                              hipStream_t stream) {
    const float* inA = (const float*)d_in[0];   // in_signal
    const float* inB = (const float*)d_in[1];   // ref_signal
    float* out = (float*)d_out;
    float4* rows = (float4*)d_ws;               // 2048 * 16 B scratch, fully rewritten each call

    hipLaunchKernelGGL(row_kernel, dim3(BB), dim3(NT), 0, stream, inA, inB, rows);
    hipLaunchKernelGGL(reduce_kernel, dim3(1), dim3(256), 0, stream, rows, out);
}